// Round 1
// baseline (1140.578 us; speedup 1.0000x reference)
//
#include <hip/hip_runtime.h>
#include <math.h>

#define D 512
#define KN 32
#define NB 8192

// ---------------- K1a: M[i,j] = sum_e w1[e,i] * w2[e,j]  (M = w1^T @ w2) ----
__global__ __launch_bounds__(256) void k_prepM(const float* __restrict__ w1,
                                               const float* __restrict__ w2,
                                               float* __restrict__ M) {
    __shared__ float As[16][17];
    __shared__ float Bs[16][17];
    int t = threadIdx.x;
    int tx = t & 15;        // local j (also local i for loads)
    int ty = t >> 4;        // local i (also local e for loads)
    int i0 = blockIdx.y * 16;
    int j0 = blockIdx.x * 16;
    float acc = 0.f;
    for (int e0 = 0; e0 < D; e0 += 16) {
        As[ty][tx] = w1[(e0 + ty) * D + i0 + tx];
        Bs[ty][tx] = w2[(e0 + ty) * D + j0 + tx];
        __syncthreads();
#pragma unroll
        for (int e = 0; e < 16; ++e)
            acc += As[e][ty] * Bs[e][tx];
        __syncthreads();
    }
    M[(i0 + ty) * D + j0 + tx] = acc;
}

// ---------------- K1b: u = w1^T b2 ; bw = b1 @ w2 ; c = b1.b2 ---------------
__global__ __launch_bounds__(512) void k_prepVec(const float* __restrict__ w1,
                                                 const float* __restrict__ b1,
                                                 const float* __restrict__ w2,
                                                 const float* __restrict__ b2,
                                                 float* __restrict__ u,
                                                 float* __restrict__ bw,
                                                 float* __restrict__ cc) {
    int t = threadIdx.x;  // 512 threads
    if (blockIdx.x == 0) {
        float acc = 0.f;
        for (int e = 0; e < D; ++e) acc += w1[e * D + t] * b2[e];
        u[t] = acc;
    } else if (blockIdx.x == 1) {
        float acc = 0.f;
        for (int e = 0; e < D; ++e) acc += b1[e] * w2[e * D + t];
        bw[t] = acc;
    } else {
        __shared__ float red[512];
        red[t] = b1[t] * b2[t];
        __syncthreads();
        for (int s = 256; s > 0; s >>= 1) {
            if (t < s) red[t] += red[t + s];
            __syncthreads();
        }
        if (t == 0) cc[0] = red[0];
    }
}

// ---------------- K2: q2 = x @ M + bw  ([8192,512] x [512,512]) -------------
// 64x64 tile, 256 threads, 4x4 micro-tile, BK=16
__global__ __launch_bounds__(256) void k_q2(const float* __restrict__ x,
                                            const float* __restrict__ M,
                                            const float* __restrict__ bw,
                                            float* __restrict__ q2) {
    __shared__ float As[16][68];  // As[e][r], stride 68 keeps float4 16B-aligned
    __shared__ float Bs[16][64];  // Bs[e][c]
    int t = threadIdx.x;
    int tr = t >> 4;          // 0..15 -> rows tr*4..tr*4+3
    int tc = t & 15;          // 0..15 -> cols tc*4..tc*4+3
    int b0 = blockIdx.x * 64;
    int c0 = blockIdx.y * 64;
    int lr = t >> 2;          // 0..63: A-load row
    int le = (t & 3) * 4;     // A-load e-offset
    int be = t >> 4;          // 0..15: B-load e
    int bc = (t & 15) * 4;    // B-load col
    float acc[4][4] = {};
    for (int e0 = 0; e0 < D; e0 += 16) {
        float4 av = *(const float4*)&x[(b0 + lr) * D + e0 + le];
        float4 bv = *(const float4*)&M[(e0 + be) * D + c0 + bc];
        As[le + 0][lr] = av.x;
        As[le + 1][lr] = av.y;
        As[le + 2][lr] = av.z;
        As[le + 3][lr] = av.w;
        *(float4*)&Bs[be][bc] = bv;
        __syncthreads();
#pragma unroll
        for (int e = 0; e < 16; ++e) {
            float4 a = *(const float4*)&As[e][tr * 4];
            float4 b = *(const float4*)&Bs[e][tc * 4];
            acc[0][0] += a.x * b.x; acc[0][1] += a.x * b.y; acc[0][2] += a.x * b.z; acc[0][3] += a.x * b.w;
            acc[1][0] += a.y * b.x; acc[1][1] += a.y * b.y; acc[1][2] += a.y * b.z; acc[1][3] += a.y * b.w;
            acc[2][0] += a.z * b.x; acc[2][1] += a.z * b.y; acc[2][2] += a.z * b.z; acc[2][3] += a.z * b.w;
            acc[3][0] += a.w * b.x; acc[3][1] += a.w * b.y; acc[3][2] += a.w * b.z; acc[3][3] += a.w * b.w;
        }
        __syncthreads();
    }
    float4 biasv = *(const float4*)&bw[c0 + tc * 4];
#pragma unroll
    for (int i = 0; i < 4; ++i) {
        float4 o;
        o.x = acc[i][0] + biasv.x;
        o.y = acc[i][1] + biasv.y;
        o.z = acc[i][2] + biasv.z;
        o.w = acc[i][3] + biasv.w;
        *(float4*)&q2[(size_t)(b0 + tr * 4 + i) * D + c0 + tc * 4] = o;
    }
}

// ---------------- K3: fused attention per row -------------------------------
// scores_k = (keys[b,k,:].q2[b,:] + qb_b) / sqrt(D); softmax; out = 0.5x+0.5*attn@V
__global__ __launch_bounds__(256) void k_attn(const float* __restrict__ x,
                                              const float* __restrict__ keys,
                                              const float* __restrict__ values,
                                              const float* __restrict__ q2,
                                              const float* __restrict__ u,
                                              const float* __restrict__ cc,
                                              float* __restrict__ out) {
    __shared__ float q2s[512];
    __shared__ float xs[512];
    __shared__ float attn[32];
    __shared__ float red[4];
    __shared__ float qbs;
    int b = blockIdx.x;
    int t = threadIdx.x;          // 256 threads = 4 waves
    int lane = t & 63;
    int wave = t >> 6;

    // stage q2 row and x row; start qb = x.u reduction
    float2 q2v = *(const float2*)&q2[(size_t)b * D + 2 * t];
    float2 xv = *(const float2*)&x[(size_t)b * D + 2 * t];
    *(float2*)&q2s[2 * t] = q2v;
    *(float2*)&xs[2 * t] = xv;
    float p = xv.x * u[2 * t] + xv.y * u[2 * t + 1];
#pragma unroll
    for (int off = 32; off; off >>= 1) p += __shfl_xor(p, off);
    if (lane == 0) red[wave] = p;
    __syncthreads();
    if (t == 0) qbs = red[0] + red[1] + red[2] + red[3] + cc[0];
    __syncthreads();

    // scores: wave w handles k = w*8 .. w*8+7
    float qb_local = qbs;
    float4 qa = *(const float4*)&q2s[lane * 4];
    float4 qc = *(const float4*)&q2s[256 + lane * 4];
#pragma unroll
    for (int kk = 0; kk < 8; ++kk) {
        int k = wave * 8 + kk;
        const float* kp = &keys[((size_t)b * KN + k) * D];
        float4 k1 = *(const float4*)&kp[lane * 4];
        float4 k2 = *(const float4*)&kp[256 + lane * 4];
        float s = qa.x * k1.x + qa.y * k1.y + qa.z * k1.z + qa.w * k1.w +
                  qc.x * k2.x + qc.y * k2.y + qc.z * k2.z + qc.w * k2.w;
#pragma unroll
        for (int off = 32; off; off >>= 1) s += __shfl_xor(s, off);
        if (lane == 0) attn[k] = (s + qb_local) * 0.04419417382415922f; // 1/sqrt(512)
    }
    __syncthreads();

    // softmax over 32 (single wave, lockstep)
    if (t < 32) {
        float m = -1e30f;
#pragma unroll
        for (int j = 0; j < 32; ++j) m = fmaxf(m, attn[j]);
        float sum = 0.f;
#pragma unroll
        for (int j = 0; j < 32; ++j) sum += expf(attn[j] - m);
        float a = expf(attn[t] - m) / sum;
        attn[t] = a;   // safe: single-wave lockstep, reads above complete first
    }
    __syncthreads();

    // combined + residual mix: out = 0.5*(x + attn@V)
    const float* vp = &values[(size_t)b * KN * D];
    float a0 = 0.f, a1 = 0.f;
#pragma unroll 8
    for (int k = 0; k < KN; ++k) {
        float ak = attn[k];
        float2 v = *(const float2*)&vp[k * D + 2 * t];
        a0 += ak * v.x;
        a1 += ak * v.y;
    }
    float2 o;
    o.x = 0.5f * (xs[2 * t] + a0);
    o.y = 0.5f * (xs[2 * t + 1] + a1);
    *(float2*)&out[(size_t)b * D + 2 * t] = o;
}

extern "C" void kernel_launch(void* const* d_in, const int* in_sizes, int n_in,
                              void* d_out, int out_size, void* d_ws, size_t ws_size,
                              hipStream_t stream) {
    const float* x = (const float*)d_in[0];
    const float* keys = (const float*)d_in[1];
    const float* values = (const float*)d_in[2];
    const float* w1 = (const float*)d_in[3];
    const float* b1 = (const float*)d_in[4];
    const float* w2 = (const float*)d_in[5];
    const float* b2 = (const float*)d_in[6];
    float* out = (float*)d_out;

    float* ws = (float*)d_ws;
    float* M = ws;                    // 512*512 = 262144
    float* u = ws + 262144;           // 512
    float* bw = ws + 262656;          // 512
    float* cc = ws + 263168;          // 1 (pad to 16)
    float* q2 = ws + 263184;          // 8192*512 = 4194304  (16B aligned)

    k_prepM<<<dim3(32, 32), 256, 0, stream>>>(w1, w2, M);
    k_prepVec<<<3, 512, 0, stream>>>(w1, b1, w2, b2, u, bw, cc);
    k_q2<<<dim3(NB / 64, D / 64), 256, 0, stream>>>(x, M, bw, q2);
    k_attn<<<NB, 256, 0, stream>>>(x, keys, values, q2, u, cc, out);
}